// Round 9
// baseline (72.703 us; speedup 1.0000x reference)
//
#include <hip/hip_runtime.h>

// out[b,c] = sum_k w[b,k] * BivariateNormalPDF(X[b,c]; params[b,k])
// B=512, K=64, C=2048.
//
// Round 9: split-K across waves. Block = 256 threads = 4 waves; wave
// (kH,pH) handles k-half kH (32 of 64 k's) on point-half pH (512 of the
// block's 1024 points, 8 pts/lane as 4 packed pairs). This cuts per-wave
// LDS coefficient reads 64x2 -> 16x3 b128 (pair-packed 48 B records,
// 16B-aligned), taking the CU LDS pipe (measured ~12 cy per ds_read_b128
// even broadcast; the R8 bottleneck at ~7.7us/CU) down to ~3.8us, under
// the ~4.9us VALU floor. Partial sums (2 per point) reduced via an 8 KB
// LDS buffer + one barrier.
// Exponent in log2 domain (wn folded in): e = A x^2+B y^2+C xy+D x+E y+F,
// acc += exp2(e); x^2,y^2,xy hoisted per lane.

typedef float v2f __attribute__((ext_vector_type(2)));

constexpr int B = 512;
constexpr int K = 64;
constexpr int C = 2048;
constexpr int BLOCK = 256;
constexpr int HALVES = 2;        // each batch's C range split across 2 blocks
constexpr int CH = C / HALVES;   // 1024 points per block
constexpr int NP = 4;            // packed point-pairs per lane (8 pts)

__global__ __launch_bounds__(BLOCK, 4) void mixture_kernel(
    const float* __restrict__ mo,   // (B, K, 6)
    const float* __restrict__ X,    // (B, C, 2)
    float* __restrict__ out)        // (B, C)
{
    __shared__ float  Pc[(K / 2) * 12];   // pair-packed coefficients (1536 B)
    __shared__ float  Rbuf[2][CH];        // partial sums per k-half (8 KB)

    const int bid  = blockIdx.x;
    const int b    = bid >> 1;
    const int h    = bid & 1;
    const int t    = threadIdx.x;
    const int lane = t & 63;
    const int wid  = t >> 6;      // 0..3
    const int kH   = wid & 1;     // k-half this wave sums
    const int pH   = wid >> 1;    // point-half this wave covers

    if (t < K) {
        const float* p6 = mo + ((size_t)(b * K + t)) * 6;
        const float w  = p6[0];
        const float m1 = p6[1];
        const float m2 = p6[2];
        const float s1 = p6[3];
        const float s2 = p6[4];
        const float r  = p6[5];

        const float omr2 = fmaf(-r, r, 1.0f);
        const float inv  = 1.0f / omr2;
        const float g    = 0.7213475204444817f * inv;   // 0.5*log2(e)/omr2
        const float i1   = 1.0f / s1;
        const float i2   = 1.0f / s2;
        const float p    = g * i1 * i1;
        const float q    = g * i2 * i2;
        const float s    = 2.0f * r * g * i1 * i2;
        const float A    = -p;
        const float Bc   = -q;
        const float Cc   = s;
        const float D    = fmaf(2.0f * p, m1, -s * m2);
        const float E    = fmaf(2.0f * q, m2, -s * m1);
        const float wn   = w * 0.15915494309189535f * i1 * i2 * sqrtf(inv);
        const float L    = log2f(fmaxf(wn, 1e-37f));
        const float F    = fmaf(-p, m1 * m1, fmaf(-q, m2 * m2, fmaf(s, m1 * m2, L)));

        // pair-packed: pair pr=(k>>1) holds 12 floats; k even -> slots 0..5,
        // k odd -> slots 6..11. Record = 48 B, 16B-aligned.
        float* dst = &Pc[(t >> 1) * 12 + (t & 1) * 6];
        dst[0] = A; dst[1] = Bc; dst[2] = Cc;
        dst[3] = D; dst[4] = E;  dst[5] = F;
    }
    __syncthreads();

    // This wave's 8 points: pair p -> float4 index pH*256 + p*64 + lane.
    const float4* Xb = (const float4*)(X + ((size_t)b * C + (size_t)h * CH) * 2);
    v2f xp[NP], yp[NP], xx[NP], yy[NP], xy[NP], acc[NP];
#pragma unroll
    for (int p = 0; p < NP; ++p) {
        const float4 f4 = Xb[pH * 256 + p * 64 + lane];
        xp[p]  = (v2f){f4.x, f4.z};
        yp[p]  = (v2f){f4.y, f4.w};
        xx[p]  = xp[p] * xp[p];
        yy[p]  = yp[p] * yp[p];
        xy[p]  = xp[p] * yp[p];
        acc[p] = (v2f){0.0f, 0.0f};
    }

    const float4* Pq = (const float4*)Pc;

#pragma unroll 4
    for (int pr = 0; pr < 16; ++pr) {
        const int pb = (kH * 16 + pr) * 3;
        const float4 q0 = Pq[pb + 0];   // A0,B0,C0,D0  (broadcast)
        const float4 q1 = Pq[pb + 1];   // E0,F0,A1,B1
        const float4 q2 = Pq[pb + 2];   // C1,D1,E1,F1

        // k even of the pair
        {
            const v2f A2 = {q0.x, q0.x}, B2 = {q0.y, q0.y}, C2 = {q0.z, q0.z};
            const v2f D2 = {q0.w, q0.w}, E2 = {q1.x, q1.x}, F2 = {q1.y, q1.y};
#pragma unroll
            for (int p = 0; p < NP; ++p) {
                v2f e = __builtin_elementwise_fma(A2, xx[p], F2);
                e     = __builtin_elementwise_fma(B2, yy[p], e);
                e     = __builtin_elementwise_fma(C2, xy[p], e);
                e     = __builtin_elementwise_fma(D2, xp[p], e);
                e     = __builtin_elementwise_fma(E2, yp[p], e);
                v2f ex;
                ex.x = __builtin_amdgcn_exp2f(e.x);
                ex.y = __builtin_amdgcn_exp2f(e.y);
                acc[p] = acc[p] + ex;
            }
        }
        // k odd of the pair
        {
            const v2f A2 = {q1.z, q1.z}, B2 = {q1.w, q1.w}, C2 = {q2.x, q2.x};
            const v2f D2 = {q2.y, q2.y}, E2 = {q2.z, q2.z}, F2 = {q2.w, q2.w};
#pragma unroll
            for (int p = 0; p < NP; ++p) {
                v2f e = __builtin_elementwise_fma(A2, xx[p], F2);
                e     = __builtin_elementwise_fma(B2, yy[p], e);
                e     = __builtin_elementwise_fma(C2, xy[p], e);
                e     = __builtin_elementwise_fma(D2, xp[p], e);
                e     = __builtin_elementwise_fma(E2, yp[p], e);
                v2f ex;
                ex.x = __builtin_amdgcn_exp2f(e.x);
                ex.y = __builtin_amdgcn_exp2f(e.y);
                acc[p] = acc[p] + ex;
            }
        }
    }

    // Write this wave's partial sums (2-way bank aliasing = free).
    {
        float2* rw = (float2*)&Rbuf[kH][pH * 512];
#pragma unroll
        for (int p = 0; p < NP; ++p)
            rw[p * 64 + lane] = make_float2(acc[p].x, acc[p].y);
    }
    __syncthreads();

    // Reduce the two k-half partials and store (coalesced float4).
    {
        const float4* r0 = (const float4*)&Rbuf[0][0];
        const float4* r1 = (const float4*)&Rbuf[1][0];
        const float4 s0 = r0[t];
        const float4 s1 = r1[t];
        float4 s;
        s.x = s0.x + s1.x;
        s.y = s0.y + s1.y;
        s.z = s0.z + s1.z;
        s.w = s0.w + s1.w;
        ((float4*)(out + (size_t)b * C + (size_t)h * CH))[t] = s;
    }
}

extern "C" void kernel_launch(void* const* d_in, const int* in_sizes, int n_in,
                              void* d_out, int out_size, void* d_ws, size_t ws_size,
                              hipStream_t stream) {
    const float* mo = (const float*)d_in[0];   // (B,K,6)
    const float* X  = (const float*)d_in[1];   // (B,C,2)
    float* out      = (float*)d_out;           // (B,C)

    mixture_kernel<<<dim3(B * HALVES), dim3(BLOCK), 0, stream>>>(mo, X, out);
}